// Round 7
// baseline (234.329 us; speedup 1.0000x reference)
//
#include <hip/hip_runtime.h>

#define NPTS 50000
#define KNB 16
#define FDIM 64
#define OUTC 64
#define FAN 1024   // KNB*FDIM
#define NBL 4      // n values per block

typedef __attribute__((ext_vector_type(4))) float f32x4;
typedef __attribute__((ext_vector_type(8))) short bf16x8;
typedef __attribute__((ext_vector_type(4))) short bf16x4;

__device__ __forceinline__ unsigned short f2bf(float f) {
    union { float f; unsigned u; } a; a.f = f;
    return (unsigned short)((a.u + 0x7fffu + ((a.u >> 16) & 1u)) >> 16);
}

// one-time (per launch) conversion of W [64][1024] f32 -> bf16 in d_ws
__global__ void wconv_kernel(const float* __restrict__ W, unsigned short* __restrict__ Wb) {
    int i = blockIdx.x * 256 + threadIdx.x;
    Wb[i] = f2bf(W[i]);
}

template<int USEWB>
__global__ __launch_bounds__(256, 4)
void paiconv_kernel(const float* __restrict__ x, const float* __restrict__ v,
                    const float* __restrict__ aw, const float* __restrict__ W,
                    const unsigned short* __restrict__ Wb,
                    const float* __restrict__ bias, const int* __restrict__ nbr,
                    float* __restrict__ out)
{
    // yel rows padded to 1032 bf16 (2064 B): phase-2 b128 reads land on rotating banks.
    // Final storage is SWIZZLED: logical (t,f) lives at [t*64 + (f ^ ((t&7)<<3))].
    // Each row ALSO serves as the phase-1 staging buffer for its own point
    // (subtiled X layout, fully consumed into registers before outputs land).
    __shared__ __align__(16) unsigned short yel[16][1032]; // 33 KB
    __shared__ int idxs[4][4][KNB];                        // 1 KB

    const int tid  = threadIdx.x;
    const int w    = tid >> 6;   // wave id = which n of the 4
    const int lane = tid & 63;
    const int cl   = lane & 15;
    const int kg   = lane >> 4;  // 16-lane group 0..3
    const int n0   = blockIdx.x * NBL;
    const int n    = n0 + w;

    // neighbor indices for this wave's n: lane l -> (batch pp, k)
    idxs[w][lane >> 4][lane & 15] = nbr[((lane >> 4) * NPTS + n) * KNB + (lane & 15)];

    // ---- B operand for phase-1 MFMA: adj[k][t]; k-map k = kg*4+j (j=0..3), j>=4 zero ----
    f32x4 v0 = *(const f32x4*)&v[n * 8];
    f32x4 v1 = *(const f32x4*)&v[n * 8 + 4];
    float vv[8] = {v0[0], v0[1], v0[2], v0[3], v1[0], v1[1], v1[2], v1[3]};
    bf16x8 badj;
    #pragma unroll
    for (int j = 0; j < 4; ++j) {
        float a = 0.f;
        #pragma unroll
        for (int s = 0; s < 8; ++s) a += vv[s] * aw[s * 256 + (kg * 4 + j) * KNB + cl];
        badj[j] = (short)f2bf(a);
    }
    #pragma unroll
    for (int j = 4; j < 8; ++j) badj[j] = 0;

    // staging lane roles: instr i loads row k=i*4+g, f = fq*4..fq*4+3 (coalesced 1KB/instr)
    const int g  = lane >> 4;
    const int fq = lane & 15;

    // ---- phase 1, batched: issue ALL 16 gather loads upfront (max prefetch depth) ----
    f32x4 xl[4][4];
    #pragma unroll
    for (int pp = 0; pp < 4; ++pp) {
        const float* xb = x + (size_t)pp * NPTS * FDIM;
        #pragma unroll
        for (int i = 0; i < 4; ++i) {
            int row = idxs[w][pp][i * 4 + g];
            xl[pp][i] = *(const f32x4*)&xb[(size_t)row * FDIM + fq * 4];
        }
    }

    // cvt + pack + subtiled stores: elem = ft*256 + k*16 + fl, ft=fq>>2, fl=4*(lane&3)
    {
        const int wbase = (fq >> 2) * 256 + 4 * (lane & 3);
        #pragma unroll
        for (int pp = 0; pp < 4; ++pp) {
            unsigned short* S = &yel[w * 4 + pp][0];
            #pragma unroll
            for (int i = 0; i < 4; ++i) {
                bf16x4 pkd;
                #pragma unroll
                for (int d = 0; d < 4; ++d) pkd[d] = (short)f2bf(xl[pp][i][d]);
                *(bf16x4*)&S[wbase + (i * 4 + g) * 16] = pkd;   // ds_write_b64, ~4-way
            }
        }
    }

    // ONE drain: all staging writes visible before transpose-reads
    asm volatile("s_waitcnt lgkmcnt(0)" ::: "memory");
    __builtin_amdgcn_sched_barrier(0);

    // transpose-read fragments (HK pattern): per-lane addr = row base + lane*8B;
    // HW delivers lane l elem j = elem[(l&15) + j*16 + (l>>4)*64] of the 512B subtile,
    // i.e. frs[pp][ft][j] = X[kg*4+j][ft*16+cl]. offset: walks the 4 f-subtiles.
    bf16x4 frs[4][4];
    #pragma unroll
    for (int pp = 0; pp < 4; ++pp) {
        unsigned ab = (unsigned)(unsigned long long)&yel[w * 4 + pp][0] + lane * 8;
        asm volatile("ds_read_b64_tr_b16 %0, %1 offset:0"    : "=v"(frs[pp][0]) : "v"(ab) : "memory");
        asm volatile("ds_read_b64_tr_b16 %0, %1 offset:512"  : "=v"(frs[pp][1]) : "v"(ab) : "memory");
        asm volatile("ds_read_b64_tr_b16 %0, %1 offset:1024" : "=v"(frs[pp][2]) : "v"(ab) : "memory");
        asm volatile("ds_read_b64_tr_b16 %0, %1 offset:1536" : "=v"(frs[pp][3]) : "v"(ab) : "memory");
    }
    asm volatile("s_waitcnt lgkmcnt(0)" ::: "memory");
    __builtin_amdgcn_sched_barrier(0);

    // 16 MFMAs (K=16 padded to 32 with zero slots) + elu + swizzled outputs
    #pragma unroll
    for (int pp = 0; pp < 4; ++pp) {
        unsigned short* S = &yel[w * 4 + pp][0];
        #pragma unroll
        for (int ft = 0; ft < 4; ++ft) {
            bf16x8 af;
            #pragma unroll
            for (int j = 0; j < 4; ++j) af[j] = frs[pp][ft][j];
            #pragma unroll
            for (int j = 4; j < 8; ++j) af[j] = 0;
            f32x4 accv = {0.f, 0.f, 0.f, 0.f};
            accv = __builtin_amdgcn_mfma_f32_16x16x32_bf16(af, badj, accv, 0, 0, 0);
            // D: row(m) = kg*4+r -> f = ft*16+kg*4+r ; col(n) = cl -> t
            const int t  = cl;
            const int fs = (ft * 16 + kg * 4) ^ ((t & 7) << 3);
            bf16x4 wv;
            #pragma unroll
            for (int r = 0; r < 4; ++r) {
                float e = accv[r];
                e = e > 0.f ? e : __expf(e) - 1.f;
                wv[r] = (short)f2bf(e);
            }
            *(bf16x4*)&S[t * 64 + fs] = wv;   // staging already consumed into frs
        }
    }

    __syncthreads();

    // ---- phase 2: wave w owns C-tile rows=16 points, cols c in [16w,16w+16) ----
    const int c = w * 16 + cl;
    f32x4 acc = {0.f, 0.f, 0.f, 0.f};
    #pragma unroll 8
    for (int kt = 0; kt < 32; ++kt) {
        const int t  = kt >> 1;
        const int fs = (((kt & 1) * 32) | (kg * 8)) ^ ((t & 7) << 3);
        bf16x8 afrag = *(const bf16x8*)&yel[cl][t * 64 + fs];   // ds_read_b128
        bf16x8 bfrag;
        const int k0 = kt * 32 + kg * 8;
        if (USEWB) {
            bfrag = *(const bf16x8*)&Wb[c * FAN + k0];
        } else {
            f32x4 w0 = *(const f32x4*)&W[c * FAN + k0];
            f32x4 w1 = *(const f32x4*)&W[c * FAN + k0 + 4];
            #pragma unroll
            for (int j = 0; j < 4; ++j) {
                bfrag[j]     = (short)f2bf(w0[j]);
                bfrag[j + 4] = (short)f2bf(w1[j]);
            }
        }
        acc = __builtin_amdgcn_mfma_f32_16x16x32_bf16(afrag, bfrag, acc, 0, 0, 0);
    }

    // epilogue: D row = kg*4 + r = local point, col = c
    float bc = bias[c];
    #pragma unroll
    for (int j = 0; j < 4; ++j) {
        int row = kg * 4 + j;
        int nn  = n0 + (row >> 2);
        int pp  = row & 3;
        float val = acc[j] + bc;
        val = val > 0.f ? val : __expf(val) - 1.f;
        if (nn == NPTS - 1) val = 0.f;   // zero_pad: last point zeroed (all b, all c)
        out[(pp * NPTS + nn) * FDIM + c] = val;
    }
}

extern "C" void kernel_launch(void* const* d_in, const int* in_sizes, int n_in,
                              void* d_out, int out_size, void* d_ws, size_t ws_size,
                              hipStream_t stream) {
    const float* x    = (const float*)d_in[0];
    const float* v    = (const float*)d_in[1];
    const float* aw   = (const float*)d_in[2];
    const float* W    = (const float*)d_in[3];
    const float* bias = (const float*)d_in[4];
    const int*   nbr  = (const int*)d_in[5];
    float* out = (float*)d_out;

    dim3 grid(NPTS / NBL), blk(256);
    if (ws_size >= (size_t)(OUTC * FAN * 2)) {
        unsigned short* Wb = (unsigned short*)d_ws;
        wconv_kernel<<<dim3(OUTC * FAN / 256), dim3(256), 0, stream>>>(W, Wb);
        paiconv_kernel<1><<<grid, blk, 0, stream>>>(x, v, aw, W, Wb, bias, nbr, out);
    } else {
        paiconv_kernel<0><<<grid, blk, 0, stream>>>(x, v, aw, W,
                                                    (const unsigned short*)nullptr,
                                                    bias, nbr, out);
    }
}